// Round 1
// baseline (1006.666 us; speedup 1.0000x reference)
//
#include <hip/hip_runtime.h>
#include <hip/hip_bf16.h>

#define NN 20000
#define EE 160000
#define CIN1 16
#define HH 32
#define MIDD 32

// ---------------- prep kernels ----------------

__global__ void count_kernel(const int* __restrict__ ei, int* __restrict__ cnt) {
    int e = blockIdx.x * 256 + threadIdx.x;
    if (e < EE) atomicAdd(&cnt[ei[EE + e]], 1);
}

__global__ void scan_kernel(const int* __restrict__ cnt, int* __restrict__ off,
                            float* __restrict__ invc) {
    __shared__ int tot[1024];
    const int t = threadIdx.x;
    const int CH = 20;                 // 1024*20 = 20480 >= 20000
    int base = t * CH;
    int loc[CH];
    int s = 0;
    #pragma unroll
    for (int r = 0; r < CH; ++r) {
        int idx = base + r;
        int c = (idx < NN) ? cnt[idx] : 0;
        loc[r] = s;
        s += c;
    }
    tot[t] = s;
    __syncthreads();
    // Hillis-Steele inclusive scan over 1024 totals
    for (int d = 1; d < 1024; d <<= 1) {
        int u = (t >= d) ? tot[t - d] : 0;
        __syncthreads();
        tot[t] += u;
        __syncthreads();
    }
    int basesum = (t == 0) ? 0 : tot[t - 1];
    #pragma unroll
    for (int r = 0; r < CH; ++r) {
        int idx = base + r;
        if (idx < NN) {
            off[idx] = basesum + loc[r];
            int c = cnt[idx];
            invc[idx] = 1.0f / fmaxf((float)c, 1.0f);
        }
    }
    if (t == 0) off[NN] = EE;
}

__global__ void scatter_kernel(const int* __restrict__ ei, const float* __restrict__ ewt,
                               const int* __restrict__ off, int* __restrict__ cur,
                               int* __restrict__ ssrc, float* __restrict__ sew) {
    int e = blockIdx.x * 256 + threadIdx.x;
    if (e < EE) {
        int d = ei[EE + e];
        int p = atomicAdd(&cur[d], 1);
        int pos = off[d] + p;
        ssrc[pos] = ei[e];
        sew[pos] = ewt[e];
    }
}

// Wcat1 = [en1_w2 (512x32) ; en1_b2 (16x32) ; root1 (16x32)]  -> 17408 floats
// Wcat2 = [en2_w2 (1024x32); en2_b2 (32x32) ; root2 (32x32)]  -> 34816 floats
__global__ void build_wcat(const float* __restrict__ w2a, const float* __restrict__ b2a,
                           const float* __restrict__ ra,
                           const float* __restrict__ w2b, const float* __restrict__ b2b,
                           const float* __restrict__ rb,
                           float* __restrict__ wc1, float* __restrict__ wc2) {
    int i = blockIdx.x * 256 + threadIdx.x;
    if (i < 17408) {
        float v = (i < 16384) ? w2a[i] : ((i < 16896) ? b2a[i - 16384] : ra[i - 16896]);
        wc1[i] = v;
    }
    if (i < 34816) {
        float v = (i < 32768) ? w2b[i] : ((i < 33792) ? b2b[i - 32768] : rb[i - 33792]);
        wc2[i] = v;
    }
}

// ---------------- fused layer kernel ----------------
// Per block: 32 nodes. Phase A: each of 4 waves builds F rows for 8 nodes
// (k = lane + 64*j maps exactly to (m = k/CIN, i = k%CIN)); F[d] =
// [inv*S (MID*CIN) | inv*S0 (CIN) | x[d] (CIN)] stored column-major in LDS
// with pad 34 (write-conflict-free, 8B-aligned reads).
// Phase B: block GEMM F(32 x K) @ Wcat(K x 32), W staged in LDS chunks,
// thread tile 2 nodes x 2 outputs. Epilogue: bias+silu (layer1 -> h1) or
// bias+silu+decode dot (layer2 -> out).

__device__ __forceinline__ float silu_f(float v) {
    return __fdividef(v, 1.0f + __expf(-v));
}

template <int CIN, bool DECODE>
__global__ __launch_bounds__(256) void layer_kernel(
    const float* __restrict__ xin, const int* __restrict__ ssrc,
    const float* __restrict__ sew, const int* __restrict__ off,
    const float* __restrict__ invc, const float* __restrict__ w1,
    const float* __restrict__ b1, const float* __restrict__ wcat,
    const float* __restrict__ bias, float* __restrict__ outp,
    const float* __restrict__ dw, const float* __restrict__ db) {
    constexpr int K = MIDD * CIN + 2 * CIN;   // 544 or 1088
    constexpr int JS = (MIDD * CIN) / 64;     // 8 or 16
    constexpr int PAD = 34;
    constexpr int BK = (CIN == 16) ? 56 : 64; // keeps layer1 under 80KB LDS

    extern __shared__ float smem[];
    float* F = smem;                 // K * PAD floats
    float* W = smem + K * PAD;       // BK * 32 floats

    const int tid = threadIdx.x;
    const int wave = tid >> 6, lane = tid & 63;
    const int g = blockIdx.x;

    // per-lane edge-MLP params: m is fixed per (lane, j)
    float wm[JS], bm[JS];
    #pragma unroll
    for (int j = 0; j < JS; ++j) {
        int m = lane / CIN + (64 / CIN) * j;
        wm[j] = w1[m];
        bm[j] = b1[m];
    }
    const int i_lane = lane % CIN;

    // ---- Phase A: build F for this block's 32 nodes ----
    for (int s = 0; s < 8; ++s) {
        int nsub = wave * 8 + s;
        int d = g * 32 + nsub;            // N = 625*32 exactly
        int e0 = off[d], e1 = off[d + 1];
        float iv = invc[d];
        float Sacc[JS];
        #pragma unroll
        for (int j = 0; j < JS; ++j) Sacc[j] = 0.0f;
        float S0 = 0.0f;
        for (int e = e0; e < e1; ++e) {
            float ew = sew[e];
            int sn = ssrc[e];
            float xv = xin[sn * CIN + i_lane];
            #pragma unroll
            for (int j = 0; j < JS; ++j) {
                float v = fmaf(ew, wm[j], bm[j]);
                float hh = silu_f(v);
                Sacc[j] = fmaf(hh, xv, Sacc[j]);
            }
            if (lane < CIN) S0 += xv;
        }
        #pragma unroll
        for (int j = 0; j < JS; ++j)
            F[(lane + 64 * j) * PAD + nsub] = Sacc[j] * iv;
        if (lane < CIN)
            F[(MIDD * CIN + lane) * PAD + nsub] = S0 * iv;
        else if (lane < 2 * CIN)
            F[(MIDD * CIN + lane) * PAD + nsub] = xin[d * CIN + (lane - CIN)];
    }
    __syncthreads();

    // ---- Phase B: GEMM F(32 x K) @ Wcat(K x 32) ----
    const int o0 = (tid & 15) * 2;
    const int q = tid >> 4;               // 0..15 -> node pair (2q, 2q+1)
    float a00 = 0.f, a01 = 0.f, a10 = 0.f, a11 = 0.f;
    for (int kc = 0; kc < K; kc += BK) {
        int klen = (K - kc < BK) ? (K - kc) : BK;
        if (kc) __syncthreads();
        int nf4 = klen * 8;               // klen*32/4 float4s
        for (int idx = tid; idx < nf4; idx += 256)
            ((float4*)W)[idx] = ((const float4*)(wcat + kc * 32))[idx];
        __syncthreads();
        for (int kk = 0; kk < klen; ++kk) {
            float2 wv = *(const float2*)&W[kk * 32 + o0];
            float2 fv = *(const float2*)&F[(kc + kk) * PAD + 2 * q];
            a00 = fmaf(fv.x, wv.x, a00);
            a01 = fmaf(fv.x, wv.y, a01);
            a10 = fmaf(fv.y, wv.x, a10);
            a11 = fmaf(fv.y, wv.y, a11);
        }
    }

    // ---- Epilogue ----
    const int n0 = g * 32 + 2 * q;
    float bb0 = bias[o0], bb1 = bias[o0 + 1];
    float v00 = a00 + bb0, v01 = a01 + bb1;
    float v10 = a10 + bb0, v11 = a11 + bb1;
    if (!DECODE) {
        float2 r0 = {silu_f(v00), silu_f(v01)};
        float2 r1 = {silu_f(v10), silu_f(v11)};
        *(float2*)&outp[(size_t)n0 * 32 + o0] = r0;
        *(float2*)&outp[(size_t)(n0 + 1) * 32 + o0] = r1;
    } else {
        float w0 = dw[o0], w1v = dw[o0 + 1];
        float p0 = silu_f(v00) * w0 + silu_f(v01) * w1v;
        float p1 = silu_f(v10) * w0 + silu_f(v11) * w1v;
        #pragma unroll
        for (int sft = 1; sft < 16; sft <<= 1) {
            p0 += __shfl_xor(p0, sft);
            p1 += __shfl_xor(p1, sft);
        }
        if ((tid & 15) == 0) {
            float d0 = db[0];
            outp[n0] = p0 + d0;
            outp[n0 + 1] = p1 + d0;
        }
    }
}

// ---------------- launch ----------------

extern "C" void kernel_launch(void* const* d_in, const int* in_sizes, int n_in,
                              void* d_out, int out_size, void* d_ws, size_t ws_size,
                              hipStream_t stream) {
    const float* x      = (const float*)d_in[0];
    const int*   ei     = (const int*)d_in[1];
    const float* ew     = (const float*)d_in[2];
    const float* en1_w1 = (const float*)d_in[3];
    const float* en1_b1 = (const float*)d_in[4];
    const float* en1_w2 = (const float*)d_in[5];
    const float* en1_b2 = (const float*)d_in[6];
    const float* root1  = (const float*)d_in[7];
    const float* bias1  = (const float*)d_in[8];
    const float* en2_w1 = (const float*)d_in[9];
    const float* en2_b1 = (const float*)d_in[10];
    const float* en2_w2 = (const float*)d_in[11];
    const float* en2_b2 = (const float*)d_in[12];
    const float* root2  = (const float*)d_in[13];
    const float* bias2  = (const float*)d_in[14];
    const float* dec_w  = (const float*)d_in[15];
    const float* dec_b  = (const float*)d_in[16];
    float* out = (float*)d_out;

    char* wp = (char*)d_ws;
    auto alloc = [&](size_t bytes) {
        char* p = wp;
        wp += (bytes + 255) & ~(size_t)255;
        return p;
    };
    int*   cnt  = (int*)alloc((size_t)NN * 4);
    int*   off  = (int*)alloc((size_t)(NN + 1) * 4);
    int*   cur  = (int*)alloc((size_t)NN * 4);
    float* invc = (float*)alloc((size_t)NN * 4);
    int*   ssrc = (int*)alloc((size_t)EE * 4);
    float* sew  = (float*)alloc((size_t)EE * 4);
    float* h1   = (float*)alloc((size_t)NN * 32 * 4);
    float* wc1  = (float*)alloc((size_t)17408 * 4);
    float* wc2  = (float*)alloc((size_t)34816 * 4);
    (void)ws_size; (void)in_sizes; (void)n_in; (void)out_size;

    hipMemsetAsync(cnt, 0, (size_t)NN * 4, stream);
    hipMemsetAsync(cur, 0, (size_t)NN * 4, stream);

    count_kernel<<<(EE + 255) / 256, 256, 0, stream>>>(ei, cnt);
    scan_kernel<<<1, 1024, 0, stream>>>(cnt, off, invc);
    scatter_kernel<<<(EE + 255) / 256, 256, 0, stream>>>(ei, ew, off, cur, ssrc, sew);
    build_wcat<<<(34816 + 255) / 256, 256, 0, stream>>>(en1_w2, en1_b2, root1,
                                                        en2_w2, en2_b2, root2, wc1, wc2);

    auto k1 = layer_kernel<16, false>;
    auto k2 = layer_kernel<32, true>;
    (void)hipFuncSetAttribute((const void*)k1,
                              hipFuncAttributeMaxDynamicSharedMemorySize, 163840);
    (void)hipFuncSetAttribute((const void*)k2,
                              hipFuncAttributeMaxDynamicSharedMemorySize, 163840);

    size_t lds1 = (size_t)(544 * 34 + 56 * 32) * 4;   // 81,152 B -> 2 blocks/CU
    size_t lds2 = (size_t)(1088 * 34 + 64 * 32) * 4;  // 156,160 B -> 1 block/CU

    layer_kernel<16, false><<<625, 256, lds1, stream>>>(
        x, ssrc, sew, off, invc, en1_w1, en1_b1, wc1, bias1, h1, nullptr, nullptr);
    layer_kernel<32, true><<<625, 256, lds2, stream>>>(
        h1, ssrc, sew, off, invc, en2_w1, en2_b1, wc2, bias2, out, dec_w, dec_b);
}

// Round 2
// 309.668 us; speedup vs baseline: 3.2508x; 3.2508x over previous
//
#include <hip/hip_runtime.h>
#include <hip/hip_bf16.h>

#define NN 20000
#define EE 160000
#define HH 32
#define MIDD 32

__device__ __forceinline__ float silu_f(float v) {
    return __fdividef(v, 1.0f + __expf(-v));
}

// ---------------- prep kernels ----------------

__global__ void count_kernel(const int* __restrict__ ei, int* __restrict__ cnt) {
    int e = blockIdx.x * 256 + threadIdx.x;
    if (e < EE) atomicAdd(&cnt[ei[EE + e]], 1);
}

__global__ void scan_kernel(const int* __restrict__ cnt, int* __restrict__ off,
                            float* __restrict__ invc) {
    __shared__ int tot[1024];
    const int t = threadIdx.x;
    const int CH = 20;                 // 1024*20 = 20480 >= 20000
    int base = t * CH;
    int loc[CH];
    int s = 0;
    #pragma unroll
    for (int r = 0; r < CH; ++r) {
        int idx = base + r;
        int c = (idx < NN) ? cnt[idx] : 0;
        loc[r] = s;
        s += c;
    }
    tot[t] = s;
    __syncthreads();
    for (int d = 1; d < 1024; d <<= 1) {
        int u = (t >= d) ? tot[t - d] : 0;
        __syncthreads();
        tot[t] += u;
        __syncthreads();
    }
    int basesum = (t == 0) ? 0 : tot[t - 1];
    #pragma unroll
    for (int r = 0; r < CH; ++r) {
        int idx = base + r;
        if (idx < NN) {
            off[idx] = basesum + loc[r];
            int c = cnt[idx];
            invc[idx] = 1.0f / fmaxf((float)c, 1.0f);
        }
    }
    if (t == 0) off[NN] = EE;
}

__global__ void scatter_kernel(const int* __restrict__ ei, const float* __restrict__ ewt,
                               const int* __restrict__ off, int* __restrict__ cur,
                               int* __restrict__ ssrc, float* __restrict__ sew) {
    int e = blockIdx.x * 256 + threadIdx.x;
    if (e < EE) {
        int d = ei[EE + e];
        int p = atomicAdd(&cur[d], 1);
        int pos = off[d] + p;
        ssrc[pos] = ei[e];
        sew[pos] = ewt[e];
    }
}

// Wcat1 = [en1_w2 (512x32) ; en1_b2 (16x32) ; root1 (16x32)]  -> 17408 floats
// Wcat2 = [en2_w2 (1024x32); en2_b2 (32x32) ; root2 (32x32)]  -> 34816 floats
__global__ void build_wcat(const float* __restrict__ w2a, const float* __restrict__ b2a,
                           const float* __restrict__ ra,
                           const float* __restrict__ w2b, const float* __restrict__ b2b,
                           const float* __restrict__ rb,
                           float* __restrict__ wc1, float* __restrict__ wc2) {
    int i = blockIdx.x * 256 + threadIdx.x;
    if (i < 17408) {
        float v = (i < 16384) ? w2a[i] : ((i < 16896) ? b2a[i - 16384] : ra[i - 16896]);
        wc1[i] = v;
    }
    if (i < 34816) {
        float v = (i < 32768) ? w2b[i] : ((i < 33792) ? b2b[i - 32768] : rb[i - 33792]);
        wc2[i] = v;
    }
}

// ---------------- split path: edge kernel ----------------
// One wave per node. Lane owns k = lane + 64*j  (m = k/CIN, i = k%CIN).
// F[d] = [inv*S (MID*CIN) | inv*S0 (CIN) | x[d] (CIN)], row-major [NN][K].
// All state in registers; no LDS; no spills (needs ~70 VGPR, cap 128).

template <int CIN>
__global__ __launch_bounds__(256, 4) void edge_kernel(
    const float* __restrict__ xin, const int* __restrict__ ssrc,
    const float* __restrict__ sew, const int* __restrict__ off,
    const float* __restrict__ invc, const float* __restrict__ w1,
    const float* __restrict__ b1, float* __restrict__ F) {
    constexpr int K = MIDD * CIN + 2 * CIN;
    constexpr int JS = (MIDD * CIN) / 64;
    const int lane = threadIdx.x & 63;
    const int d = (blockIdx.x * 256 + threadIdx.x) >> 6;   // 5000 blocks * 4 waves = NN
    const int i_lane = lane % CIN;

    float wm[JS], bm[JS];
    #pragma unroll
    for (int j = 0; j < JS; ++j) {
        int m = lane / CIN + (64 / CIN) * j;
        wm[j] = w1[m];
        bm[j] = b1[m];
    }
    float Sacc[JS];
    #pragma unroll
    for (int j = 0; j < JS; ++j) Sacc[j] = 0.0f;
    float S0 = 0.0f;

    const int e0 = off[d], e1 = off[d + 1];
    const float iv = invc[d];
    for (int e = e0; e < e1; ++e) {
        float ew = sew[e];
        int sn = ssrc[e];
        float xv = xin[sn * CIN + i_lane];
        #pragma unroll
        for (int j = 0; j < JS; ++j) {
            float hh = silu_f(fmaf(ew, wm[j], bm[j]));
            Sacc[j] = fmaf(hh, xv, Sacc[j]);
        }
        S0 += xv;
    }

    float* Fr = F + (size_t)d * K;
    #pragma unroll
    for (int j = 0; j < JS; ++j) Fr[lane + 64 * j] = Sacc[j] * iv;
    if (lane < CIN)
        Fr[MIDD * CIN + lane] = S0 * iv;
    else if (lane < 2 * CIN)
        Fr[MIDD * CIN + lane] = xin[d * CIN + (lane - CIN)];
}

// ---------------- split path: gemm kernel ----------------
// out(NN x 32) = F(NN x K) @ Wcat(K x 32), 64-node M-tile, BK=64 chunks.
// Ft staged transposed [k][node] pad 66 (float2 reads conflict-free, writes
// 4-way worst). Wt [k][32] read as broadcast float4. Thread: node pair 2q,
// output quad o0. Epilogue: bias+silu (layer1) or bias+silu+decode (layer2).

template <int CIN, bool DECODE>
__global__ __launch_bounds__(256, 4) void gemm_kernel(
    const float* __restrict__ F, const float* __restrict__ wcat,
    const float* __restrict__ bias, float* __restrict__ outp,
    const float* __restrict__ dw, const float* __restrict__ db) {
    constexpr int K = MIDD * CIN + 2 * CIN;
    constexpr int BK = 64;
    constexpr int LDF = 66;
    __shared__ float Ft[BK * LDF];
    __shared__ float Wt[BK * 32];

    const int t = threadIdx.x;
    const int m0 = blockIdx.x * 64;
    const int q = t >> 3;            // 0..31 -> node pair (2q, 2q+1)
    const int o0 = (t & 7) * 4;      // output quad

    float4 a0 = make_float4(0.f, 0.f, 0.f, 0.f);
    float4 a1 = make_float4(0.f, 0.f, 0.f, 0.f);

    for (int kc = 0; kc < K; kc += BK) {
        const int klen = (K - kc < BK) ? (K - kc) : BK;   // 64, tail 32 (layer1)
        if (kc) __syncthreads();
        const int lsh = (klen == 64) ? 4 : 3;             // float4s per row
        const int nf4 = 64 << lsh;
        for (int idx = t; idx < nf4; idx += 256) {
            int r = idx >> lsh;
            int c = (idx & ((1 << lsh) - 1)) << 2;
            int gr = m0 + r;
            float4 v = make_float4(0.f, 0.f, 0.f, 0.f);
            if (gr < NN) v = *(const float4*)(F + (size_t)gr * K + kc + c);
            Ft[(c + 0) * LDF + r] = v.x;
            Ft[(c + 1) * LDF + r] = v.y;
            Ft[(c + 2) * LDF + r] = v.z;
            Ft[(c + 3) * LDF + r] = v.w;
        }
        for (int idx = t; idx < klen * 8; idx += 256)
            ((float4*)Wt)[idx] = ((const float4*)(wcat + kc * 32))[idx];
        __syncthreads();
        #pragma unroll 4
        for (int kk = 0; kk < klen; ++kk) {
            float2 fv = *(const float2*)&Ft[kk * LDF + 2 * q];
            float4 wv = *(const float4*)&Wt[kk * 32 + o0];
            a0.x = fmaf(fv.x, wv.x, a0.x);
            a0.y = fmaf(fv.x, wv.y, a0.y);
            a0.z = fmaf(fv.x, wv.z, a0.z);
            a0.w = fmaf(fv.x, wv.w, a0.w);
            a1.x = fmaf(fv.y, wv.x, a1.x);
            a1.y = fmaf(fv.y, wv.y, a1.y);
            a1.z = fmaf(fv.y, wv.z, a1.z);
            a1.w = fmaf(fv.y, wv.w, a1.w);
        }
    }

    const int n0 = m0 + 2 * q;
    const float b0 = bias[o0], b1v = bias[o0 + 1], b2v = bias[o0 + 2], b3v = bias[o0 + 3];
    if (!DECODE) {
        if (n0 < NN) {
            float4 r;
            r.x = silu_f(a0.x + b0);
            r.y = silu_f(a0.y + b1v);
            r.z = silu_f(a0.z + b2v);
            r.w = silu_f(a0.w + b3v);
            *(float4*)(outp + (size_t)n0 * 32 + o0) = r;
        }
        if (n0 + 1 < NN) {
            float4 r;
            r.x = silu_f(a1.x + b0);
            r.y = silu_f(a1.y + b1v);
            r.z = silu_f(a1.z + b2v);
            r.w = silu_f(a1.w + b3v);
            *(float4*)(outp + (size_t)(n0 + 1) * 32 + o0) = r;
        }
    } else {
        const float w0 = dw[o0], w1v = dw[o0 + 1], w2v = dw[o0 + 2], w3v = dw[o0 + 3];
        float p0 = silu_f(a0.x + b0) * w0 + silu_f(a0.y + b1v) * w1v +
                   silu_f(a0.z + b2v) * w2v + silu_f(a0.w + b3v) * w3v;
        float p1 = silu_f(a1.x + b0) * w0 + silu_f(a1.y + b1v) * w1v +
                   silu_f(a1.z + b2v) * w2v + silu_f(a1.w + b3v) * w3v;
        p0 += __shfl_xor(p0, 1); p0 += __shfl_xor(p0, 2); p0 += __shfl_xor(p0, 4);
        p1 += __shfl_xor(p1, 1); p1 += __shfl_xor(p1, 2); p1 += __shfl_xor(p1, 4);
        if ((t & 7) == 0) {
            float dbv = db[0];
            if (n0 < NN) outp[n0] = p0 + dbv;
            if (n0 + 1 < NN) outp[n0 + 1] = p1 + dbv;
        }
    }
}

// ---------------- fallback fused layer kernel (round-1, known-correct) -----

template <int CIN, bool DECODE>
__global__ __launch_bounds__(256) void layer_kernel(
    const float* __restrict__ xin, const int* __restrict__ ssrc,
    const float* __restrict__ sew, const int* __restrict__ off,
    const float* __restrict__ invc, const float* __restrict__ w1,
    const float* __restrict__ b1, const float* __restrict__ wcat,
    const float* __restrict__ bias, float* __restrict__ outp,
    const float* __restrict__ dw, const float* __restrict__ db) {
    constexpr int K = MIDD * CIN + 2 * CIN;
    constexpr int JS = (MIDD * CIN) / 64;
    constexpr int PAD = 34;
    constexpr int BK = (CIN == 16) ? 56 : 64;

    extern __shared__ float smem[];
    float* F = smem;
    float* W = smem + K * PAD;

    const int tid = threadIdx.x;
    const int wave = tid >> 6, lane = tid & 63;
    const int g = blockIdx.x;

    float wm[JS], bm[JS];
    #pragma unroll
    for (int j = 0; j < JS; ++j) {
        int m = lane / CIN + (64 / CIN) * j;
        wm[j] = w1[m];
        bm[j] = b1[m];
    }
    const int i_lane = lane % CIN;

    for (int s = 0; s < 8; ++s) {
        int nsub = wave * 8 + s;
        int d = g * 32 + nsub;
        int e0 = off[d], e1 = off[d + 1];
        float iv = invc[d];
        float Sacc[JS];
        #pragma unroll
        for (int j = 0; j < JS; ++j) Sacc[j] = 0.0f;
        float S0 = 0.0f;
        for (int e = e0; e < e1; ++e) {
            float ew = sew[e];
            int sn = ssrc[e];
            float xv = xin[sn * CIN + i_lane];
            #pragma unroll
            for (int j = 0; j < JS; ++j) {
                float v = fmaf(ew, wm[j], bm[j]);
                Sacc[j] = fmaf(silu_f(v), xv, Sacc[j]);
            }
            if (lane < CIN) S0 += xv;
        }
        #pragma unroll
        for (int j = 0; j < JS; ++j)
            F[(lane + 64 * j) * PAD + nsub] = Sacc[j] * iv;
        if (lane < CIN)
            F[(MIDD * CIN + lane) * PAD + nsub] = S0 * iv;
        else if (lane < 2 * CIN)
            F[(MIDD * CIN + lane) * PAD + nsub] = xin[d * CIN + (lane - CIN)];
    }
    __syncthreads();

    const int o0 = (tid & 15) * 2;
    const int q = tid >> 4;
    float a00 = 0.f, a01 = 0.f, a10 = 0.f, a11 = 0.f;
    for (int kc = 0; kc < K; kc += BK) {
        int klen = (K - kc < BK) ? (K - kc) : BK;
        if (kc) __syncthreads();
        int nf4 = klen * 8;
        for (int idx = tid; idx < nf4; idx += 256)
            ((float4*)W)[idx] = ((const float4*)(wcat + kc * 32))[idx];
        __syncthreads();
        for (int kk = 0; kk < klen; ++kk) {
            float2 wv = *(const float2*)&W[kk * 32 + o0];
            float2 fv = *(const float2*)&F[(kc + kk) * PAD + 2 * q];
            a00 = fmaf(fv.x, wv.x, a00);
            a01 = fmaf(fv.x, wv.y, a01);
            a10 = fmaf(fv.y, wv.x, a10);
            a11 = fmaf(fv.y, wv.y, a11);
        }
    }

    const int n0 = g * 32 + 2 * q;
    float bb0 = bias[o0], bb1 = bias[o0 + 1];
    float v00 = a00 + bb0, v01 = a01 + bb1;
    float v10 = a10 + bb0, v11 = a11 + bb1;
    if (!DECODE) {
        float2 r0 = {silu_f(v00), silu_f(v01)};
        float2 r1 = {silu_f(v10), silu_f(v11)};
        *(float2*)&outp[(size_t)n0 * 32 + o0] = r0;
        *(float2*)&outp[(size_t)(n0 + 1) * 32 + o0] = r1;
    } else {
        float w0 = dw[o0], w1v = dw[o0 + 1];
        float p0 = silu_f(v00) * w0 + silu_f(v01) * w1v;
        float p1 = silu_f(v10) * w0 + silu_f(v11) * w1v;
        #pragma unroll
        for (int sft = 1; sft < 16; sft <<= 1) {
            p0 += __shfl_xor(p0, sft);
            p1 += __shfl_xor(p1, sft);
        }
        if ((tid & 15) == 0) {
            float d0 = db[0];
            outp[n0] = p0 + d0;
            outp[n0 + 1] = p1 + d0;
        }
    }
}

// ---------------- launch ----------------

extern "C" void kernel_launch(void* const* d_in, const int* in_sizes, int n_in,
                              void* d_out, int out_size, void* d_ws, size_t ws_size,
                              hipStream_t stream) {
    const float* x      = (const float*)d_in[0];
    const int*   ei     = (const int*)d_in[1];
    const float* ew     = (const float*)d_in[2];
    const float* en1_w1 = (const float*)d_in[3];
    const float* en1_b1 = (const float*)d_in[4];
    const float* en1_w2 = (const float*)d_in[5];
    const float* en1_b2 = (const float*)d_in[6];
    const float* root1  = (const float*)d_in[7];
    const float* bias1  = (const float*)d_in[8];
    const float* en2_w1 = (const float*)d_in[9];
    const float* en2_b1 = (const float*)d_in[10];
    const float* en2_w2 = (const float*)d_in[11];
    const float* en2_b2 = (const float*)d_in[12];
    const float* root2  = (const float*)d_in[13];
    const float* bias2  = (const float*)d_in[14];
    const float* dec_w  = (const float*)d_in[15];
    const float* dec_b  = (const float*)d_in[16];
    float* out = (float*)d_out;
    (void)in_sizes; (void)n_in; (void)out_size;

    char* wp = (char*)d_ws;
    auto alloc = [&](size_t bytes) {
        char* p = wp;
        wp += (bytes + 255) & ~(size_t)255;
        return p;
    };
    int*   cnt  = (int*)alloc((size_t)NN * 4);
    int*   off  = (int*)alloc((size_t)(NN + 1) * 4);
    int*   cur  = (int*)alloc((size_t)NN * 4);
    float* invc = (float*)alloc((size_t)NN * 4);
    int*   ssrc = (int*)alloc((size_t)EE * 4);
    float* sew  = (float*)alloc((size_t)EE * 4);
    float* h1   = (float*)alloc((size_t)NN * 32 * 4);
    float* wc1  = (float*)alloc((size_t)17408 * 4);
    float* wc2  = (float*)alloc((size_t)34816 * 4);
    float* Fbuf = (float*)alloc((size_t)NN * 1088 * 4);   // F1 aliases F2 (disjoint lifetimes)
    const size_t required = (size_t)(wp - (char*)d_ws);

    hipMemsetAsync(cnt, 0, (size_t)NN * 4, stream);
    hipMemsetAsync(cur, 0, (size_t)NN * 4, stream);

    count_kernel<<<(EE + 255) / 256, 256, 0, stream>>>(ei, cnt);
    scan_kernel<<<1, 1024, 0, stream>>>(cnt, off, invc);
    scatter_kernel<<<(EE + 255) / 256, 256, 0, stream>>>(ei, ew, off, cur, ssrc, sew);
    build_wcat<<<(34816 + 255) / 256, 256, 0, stream>>>(en1_w2, en1_b2, root1,
                                                        en2_w2, en2_b2, root2, wc1, wc2);

    if (ws_size >= required) {
        // split path
        edge_kernel<16><<<5000, 256, 0, stream>>>(x, ssrc, sew, off, invc,
                                                  en1_w1, en1_b1, Fbuf);
        gemm_kernel<16, false><<<(NN + 63) / 64, 256, 0, stream>>>(
            Fbuf, wc1, bias1, h1, nullptr, nullptr);
        edge_kernel<32><<<5000, 256, 0, stream>>>(h1, ssrc, sew, off, invc,
                                                  en2_w1, en2_b1, Fbuf);
        gemm_kernel<32, true><<<(NN + 63) / 64, 256, 0, stream>>>(
            Fbuf, wc2, bias2, out, dec_w, dec_b);
    } else {
        // fallback: round-1 fused path (fits in ~4.4 MB)
        auto k1 = layer_kernel<16, false>;
        auto k2 = layer_kernel<32, true>;
        (void)hipFuncSetAttribute((const void*)k1,
                                  hipFuncAttributeMaxDynamicSharedMemorySize, 163840);
        (void)hipFuncSetAttribute((const void*)k2,
                                  hipFuncAttributeMaxDynamicSharedMemorySize, 163840);
        size_t lds1 = (size_t)(544 * 34 + 56 * 32) * 4;
        size_t lds2 = (size_t)(1088 * 34 + 64 * 32) * 4;
        layer_kernel<16, false><<<625, 256, lds1, stream>>>(
            x, ssrc, sew, off, invc, en1_w1, en1_b1, wc1, bias1, h1, nullptr, nullptr);
        layer_kernel<32, true><<<625, 256, lds2, stream>>>(
            h1, ssrc, sew, off, invc, en2_w1, en2_b1, wc2, bias2, out, dec_w, dec_b);
    }
}

// Round 3
// 179.600 us; speedup vs baseline: 5.6050x; 1.7242x over previous
//
#include <hip/hip_runtime.h>
#include <hip/hip_bf16.h>

#define NN 20000
#define EE 160000
#define HH 32
#define MIDD 32

typedef _Float16 f16x4 __attribute__((ext_vector_type(4)));
typedef _Float16 f16x8 __attribute__((ext_vector_type(8)));
typedef float f32x4 __attribute__((ext_vector_type(4)));

__device__ __forceinline__ float silu_f(float v) {
    return __fdividef(v, 1.0f + __expf(-v));
}

// ---------------- prep kernels ----------------

__global__ void count_kernel(const int* __restrict__ ei, int* __restrict__ cnt) {
    int e = blockIdx.x * 256 + threadIdx.x;
    if (e < EE) atomicAdd(&cnt[ei[EE + e]], 1);
}

__global__ void scan_kernel(const int* __restrict__ cnt, int* __restrict__ off,
                            float* __restrict__ invc) {
    __shared__ int tot[1024];
    const int t = threadIdx.x;
    const int CH = 20;
    int base = t * CH;
    int loc[CH];
    int s = 0;
    #pragma unroll
    for (int r = 0; r < CH; ++r) {
        int idx = base + r;
        int c = (idx < NN) ? cnt[idx] : 0;
        loc[r] = s;
        s += c;
    }
    tot[t] = s;
    __syncthreads();
    for (int d = 1; d < 1024; d <<= 1) {
        int u = (t >= d) ? tot[t - d] : 0;
        __syncthreads();
        tot[t] += u;
        __syncthreads();
    }
    int basesum = (t == 0) ? 0 : tot[t - 1];
    #pragma unroll
    for (int r = 0; r < CH; ++r) {
        int idx = base + r;
        if (idx < NN) {
            off[idx] = basesum + loc[r];
            int c = cnt[idx];
            invc[idx] = 1.0f / fmaxf((float)c, 1.0f);
        }
    }
    if (t == 0) off[NN] = EE;
}

__global__ void scatter_kernel(const int* __restrict__ ei, const float* __restrict__ ewt,
                               const int* __restrict__ off, int* __restrict__ cur,
                               int* __restrict__ ssrc, float* __restrict__ sew) {
    int e = blockIdx.x * 256 + threadIdx.x;
    if (e < EE) {
        int d = ei[EE + e];
        int p = atomicAdd(&cur[d], 1);
        int pos = off[d] + p;
        ssrc[pos] = ei[e];
        sew[pos] = ewt[e];
    }
}

// Wt1[o][k] (32 x 544) fp16, Wt2[o][k] (32 x 1088) fp16 — transposed Wcat.
// Wcat rows: [w2 (MID*CIN) ; b2 (CIN) ; root (CIN)].
__global__ void build_wt(const float* __restrict__ w2a, const float* __restrict__ b2a,
                         const float* __restrict__ ra,
                         const float* __restrict__ w2b, const float* __restrict__ b2b,
                         const float* __restrict__ rb,
                         _Float16* __restrict__ Wt1, _Float16* __restrict__ Wt2) {
    int idx = blockIdx.x * 256 + threadIdx.x;
    if (idx < 17408) {                       // 32 * 544
        int o = idx / 544, k = idx % 544;
        float v = (k < 512) ? w2a[k * 32 + o]
                : (k < 528) ? b2a[(k - 512) * 32 + o]
                            : ra[(k - 528) * 32 + o];
        Wt1[o * 544 + k] = (_Float16)v;
    } else if (idx < 52224) {                // + 32 * 1088
        int j = idx - 17408;
        int o = j / 1088, k = j % 1088;
        float v = (k < 1024) ? w2b[k * 32 + o]
                : (k < 1056) ? b2b[(k - 1024) * 32 + o]
                             : rb[(k - 1056) * 32 + o];
        Wt2[o * 1088 + k] = (_Float16)v;
    }
}

// ---------------- edge kernel (shared-silu + shuffle broadcast) ------------
// One wave per node. h[m]=silu(ew*w1[m]+b1[m]) computed ONCE per edge by
// lane m (=lane&31), broadcast to consumers via __shfl. Lane owns
// k = lane + 64*j (m = k/CIN, i = k%CIN). F row (fp16):
// [inv*S (32*CIN) | inv*S0 (CIN) | x[d] (CIN)], K = 34*CIN.

template <int CIN>
__global__ __launch_bounds__(256, 4) void edge_kernel(
    const float* __restrict__ xin, const int* __restrict__ ssrc,
    const float* __restrict__ sew, const int* __restrict__ off,
    const float* __restrict__ invc, const float* __restrict__ w1,
    const float* __restrict__ b1, _Float16* __restrict__ F) {
    constexpr int K = 34 * CIN;
    constexpr int JS = (32 * CIN) / 64;
    const int lane = threadIdx.x & 63;
    const int d = (blockIdx.x * 256 + threadIdx.x) >> 6;   // 5000 blocks * 4 waves
    const int i_lane = lane % CIN;

    const float w1v = w1[lane & 31];
    const float b1v = b1[lane & 31];
    int srcl[JS];
    #pragma unroll
    for (int j = 0; j < JS; ++j) srcl[j] = lane / CIN + (64 / CIN) * j;

    float Sacc[JS];
    #pragma unroll
    for (int j = 0; j < JS; ++j) Sacc[j] = 0.0f;
    float S0 = 0.0f;

    const int e0 = off[d], e1 = off[d + 1];
    const float iv = invc[d];
    for (int e = e0; e < e1; ++e) {
        float ew = sew[e];
        int sn = ssrc[e];
        float hv = silu_f(fmaf(ew, w1v, b1v));
        float xv = xin[sn * CIN + i_lane];
        #pragma unroll
        for (int j = 0; j < JS; ++j)
            Sacc[j] = fmaf(__shfl(hv, srcl[j]), xv, Sacc[j]);
        S0 += xv;
    }

    _Float16* Fr = F + (size_t)d * K;
    #pragma unroll
    for (int j = 0; j < JS; ++j) Fr[lane + 64 * j] = (_Float16)(Sacc[j] * iv);
    if (lane < CIN)
        Fr[32 * CIN + lane] = (_Float16)(S0 * iv);
    else if (lane < 2 * CIN)
        Fr[32 * CIN + lane] = (_Float16)xin[d * CIN + (lane - CIN)];
}

// ---------------- MFMA gemm: out(NN x 32) = F(NN x K) @ Wcat(K x 32) -------
// 32-node tile/block (grid 625). F tile staged whole in LDS (fp16, LDK=K+8).
// 4 waves: h = w&1 -> node half (16), kq = w>>1 -> K half; LDS reduce.
// Per K-step(32): A-frag 2x b64 from LDS; B-frags (2 o-halves) from global
// (L2-resident Wt). mfma_f32_16x16x32_f16, fp32 accum.
// Frag layout: A row m=l&15, k=(l>>4)*4+j in halves {k, k+16}; B col n=l&15,
// same k. D: col=l&15, row=(l>>4)*4+r  [m89-verified].

template <int CIN, bool DECODE>
__global__ __launch_bounds__(256) void gemm_mfma(
    const _Float16* __restrict__ F, const _Float16* __restrict__ Wt,
    const float* __restrict__ bias, float* __restrict__ outp,
    const float* __restrict__ dw, const float* __restrict__ db) {
    constexpr int K = 34 * CIN;
    constexpr int LDK = K + 8;
    extern __shared__ char smem[];
    _Float16* Fl = (_Float16*)smem;
    float* red = (float*)(smem + 32 * LDK * 2);

    const int t = threadIdx.x;
    const int n0 = blockIdx.x * 32;

    // stage F tile: 32 rows x K fp16, vectorized 16B units
    constexpr int UPR = K / 8;            // 16B units per row
    for (int u = t; u < 32 * UPR; u += 256) {
        int r = u / UPR, c = u % UPR;
        float4 v = *(const float4*)(F + (size_t)(n0 + r) * K + c * 8);
        *(float4*)((char*)Fl + ((size_t)r * LDK + c * 8) * 2) = v;
    }
    __syncthreads();

    const int l = t & 63, w = t >> 6;
    const int h = w & 1, kq = w >> 1;
    const int o16 = l & 15, g = l >> 4;

    const _Float16* Arow = Fl + (size_t)(h * 16 + o16) * LDK + g * 4;
    const _Float16* B0 = Wt + (size_t)o16 * K + g * 4;
    const _Float16* B1 = Wt + (size_t)(o16 + 16) * K + g * 4;

    f32x4 acc0 = {0.f, 0.f, 0.f, 0.f};
    f32x4 acc1 = {0.f, 0.f, 0.f, 0.f};

    constexpr int steps = K / 32;
    constexpr int mid = (steps + 1) / 2;
    const int sb = kq ? mid : 0;
    const int se = kq ? steps : mid;
    for (int s = sb; s < se; ++s) {
        const int k0 = s * 32;
        f16x4 alo = *(const f16x4*)(Arow + k0);
        f16x4 ahi = *(const f16x4*)(Arow + k0 + 16);
        f16x4 b0l = *(const f16x4*)(B0 + k0);
        f16x4 b0h = *(const f16x4*)(B0 + k0 + 16);
        f16x4 b1l = *(const f16x4*)(B1 + k0);
        f16x4 b1h = *(const f16x4*)(B1 + k0 + 16);
        f16x8 a, bb0, bb1;
        #pragma unroll
        for (int j = 0; j < 4; ++j) {
            a[j] = alo[j];  a[j + 4] = ahi[j];
            bb0[j] = b0l[j]; bb0[j + 4] = b0h[j];
            bb1[j] = b1l[j]; bb1[j + 4] = b1h[j];
        }
        acc0 = __builtin_amdgcn_mfma_f32_16x16x32_f16(a, bb0, acc0, 0, 0, 0);
        acc1 = __builtin_amdgcn_mfma_f32_16x16x32_f16(a, bb1, acc1, 0, 0, 0);
    }

    // K-half reduction through LDS
    if (kq == 1) {
        #pragma unroll
        for (int r = 0; r < 4; ++r) {
            red[h * 1024 + (g * 4 + r) * 32 + o16]      = acc0[r];
            red[h * 1024 + (g * 4 + r) * 32 + 16 + o16] = acc1[r];
        }
    }
    __syncthreads();
    if (kq == 0) {
        #pragma unroll
        for (int r = 0; r < 4; ++r) {
            acc0[r] += red[h * 1024 + (g * 4 + r) * 32 + o16];
            acc1[r] += red[h * 1024 + (g * 4 + r) * 32 + 16 + o16];
        }
        const float bb0 = bias[o16], bb1 = bias[o16 + 16];
        const int nrow = n0 + h * 16 + g * 4;
        if (!DECODE) {
            #pragma unroll
            for (int r = 0; r < 4; ++r) {
                outp[(size_t)(nrow + r) * 32 + o16]      = silu_f(acc0[r] + bb0);
                outp[(size_t)(nrow + r) * 32 + 16 + o16] = silu_f(acc1[r] + bb1);
            }
        } else {
            const float w0 = dw[o16], w1v = dw[o16 + 16];
            const float dbv = db[0];
            #pragma unroll
            for (int r = 0; r < 4; ++r) {
                float p = silu_f(acc0[r] + bb0) * w0 + silu_f(acc1[r] + bb1) * w1v;
                p += __shfl_xor(p, 1);
                p += __shfl_xor(p, 2);
                p += __shfl_xor(p, 4);
                p += __shfl_xor(p, 8);
                if (o16 == 0) outp[nrow + r] = p + dbv;
            }
        }
    }
}

// ---------------- launch ----------------

extern "C" void kernel_launch(void* const* d_in, const int* in_sizes, int n_in,
                              void* d_out, int out_size, void* d_ws, size_t ws_size,
                              hipStream_t stream) {
    const float* x      = (const float*)d_in[0];
    const int*   ei     = (const int*)d_in[1];
    const float* ew     = (const float*)d_in[2];
    const float* en1_w1 = (const float*)d_in[3];
    const float* en1_b1 = (const float*)d_in[4];
    const float* en1_w2 = (const float*)d_in[5];
    const float* en1_b2 = (const float*)d_in[6];
    const float* root1  = (const float*)d_in[7];
    const float* bias1  = (const float*)d_in[8];
    const float* en2_w1 = (const float*)d_in[9];
    const float* en2_b1 = (const float*)d_in[10];
    const float* en2_w2 = (const float*)d_in[11];
    const float* en2_b2 = (const float*)d_in[12];
    const float* root2  = (const float*)d_in[13];
    const float* bias2  = (const float*)d_in[14];
    const float* dec_w  = (const float*)d_in[15];
    const float* dec_b  = (const float*)d_in[16];
    float* out = (float*)d_out;
    (void)in_sizes; (void)n_in; (void)out_size; (void)ws_size;

    char* wp = (char*)d_ws;
    auto alloc = [&](size_t bytes) {
        char* p = wp;
        wp += (bytes + 255) & ~(size_t)255;
        return p;
    };
    int*      cnt  = (int*)alloc((size_t)NN * 4);
    int*      off  = (int*)alloc((size_t)(NN + 1) * 4);
    int*      cur  = (int*)alloc((size_t)NN * 4);
    float*    invc = (float*)alloc((size_t)NN * 4);
    int*      ssrc = (int*)alloc((size_t)EE * 4);
    float*    sew  = (float*)alloc((size_t)EE * 4);
    float*    h1   = (float*)alloc((size_t)NN * 32 * 4);
    _Float16* Wt1  = (_Float16*)alloc((size_t)17408 * 2);
    _Float16* Wt2  = (_Float16*)alloc((size_t)34816 * 2);
    _Float16* F16  = (_Float16*)alloc((size_t)NN * 1088 * 2);

    hipMemsetAsync(cnt, 0, (size_t)NN * 4, stream);
    hipMemsetAsync(cur, 0, (size_t)NN * 4, stream);

    count_kernel<<<(EE + 255) / 256, 256, 0, stream>>>(ei, cnt);
    scan_kernel<<<1, 1024, 0, stream>>>(cnt, off, invc);
    scatter_kernel<<<(EE + 255) / 256, 256, 0, stream>>>(ei, ew, off, cur, ssrc, sew);
    build_wt<<<(52224 + 255) / 256, 256, 0, stream>>>(en1_w2, en1_b2, root1,
                                                      en2_w2, en2_b2, root2, Wt1, Wt2);

    auto g1 = gemm_mfma<16, false>;
    auto g2 = gemm_mfma<32, true>;
    (void)hipFuncSetAttribute((const void*)g1,
                              hipFuncAttributeMaxDynamicSharedMemorySize, 163840);
    (void)hipFuncSetAttribute((const void*)g2,
                              hipFuncAttributeMaxDynamicSharedMemorySize, 163840);

    const size_t lds1 = (size_t)32 * (544 + 8) * 2 + 8192;   // 35328 + 8192
    const size_t lds2 = (size_t)32 * (1088 + 8) * 2 + 8192;  // 70144 + 8192

    edge_kernel<16><<<5000, 256, 0, stream>>>(x, ssrc, sew, off, invc,
                                              en1_w1, en1_b1, F16);
    gemm_mfma<16, false><<<625, 256, lds1, stream>>>(F16, Wt1, bias1, h1,
                                                     nullptr, nullptr);
    edge_kernel<32><<<5000, 256, 0, stream>>>(h1, ssrc, sew, off, invc,
                                              en2_w1, en2_b1, F16);
    gemm_mfma<32, true><<<625, 256, lds2, stream>>>(F16, Wt2, bias2, out,
                                                    dec_w, dec_b);
}

// Round 4
// 174.216 us; speedup vs baseline: 5.7783x; 1.0309x over previous
//
#include <hip/hip_runtime.h>
#include <hip/hip_bf16.h>

#define NN 20000
#define EE 160000
#define HH 32
#define MIDD 32

typedef _Float16 f16x4 __attribute__((ext_vector_type(4)));
typedef _Float16 f16x8 __attribute__((ext_vector_type(8)));
typedef float f32x4 __attribute__((ext_vector_type(4)));

__device__ __forceinline__ float silu_f(float v) {
    return __fdividef(v, 1.0f + __expf(-v));
}

// ---------------- prep kernels ----------------

__global__ void count_kernel(const int* __restrict__ ei, int* __restrict__ cnt) {
    int e = blockIdx.x * 256 + threadIdx.x;
    if (e < EE) atomicAdd(&cnt[ei[EE + e]], 1);
}

__global__ void scan_kernel(const int* __restrict__ cnt, int* __restrict__ off,
                            float* __restrict__ invc) {
    __shared__ int tot[1024];
    const int t = threadIdx.x;
    const int CH = 20;
    int base = t * CH;
    int loc[CH];
    int s = 0;
    #pragma unroll
    for (int r = 0; r < CH; ++r) {
        int idx = base + r;
        int c = (idx < NN) ? cnt[idx] : 0;
        loc[r] = s;
        s += c;
    }
    tot[t] = s;
    __syncthreads();
    for (int d = 1; d < 1024; d <<= 1) {
        int u = (t >= d) ? tot[t - d] : 0;
        __syncthreads();
        tot[t] += u;
        __syncthreads();
    }
    int basesum = (t == 0) ? 0 : tot[t - 1];
    #pragma unroll
    for (int r = 0; r < CH; ++r) {
        int idx = base + r;
        if (idx < NN) {
            off[idx] = basesum + loc[r];
            int c = cnt[idx];
            invc[idx] = 1.0f / fmaxf((float)c, 1.0f);
        }
    }
    if (t == 0) off[NN] = EE;
}

__global__ void scatter_kernel(const int* __restrict__ ei, const float* __restrict__ ewt,
                               const int* __restrict__ off, int* __restrict__ cur,
                               int* __restrict__ ssrc, float* __restrict__ sew) {
    int e = blockIdx.x * 256 + threadIdx.x;
    if (e < EE) {
        int d = ei[EE + e];
        int p = atomicAdd(&cur[d], 1);
        int pos = off[d] + p;
        ssrc[pos] = ei[e];
        sew[pos] = ewt[e];
    }
}

// Wt[o][k] fp16 transposed weights. S-part k = 32*i + m  ->  w2[m*(CIN*32)+i*32+o];
// tail1 k = 32*CIN + t -> b2[t*32+o]; tail2 k = 33*CIN + t -> root[t*32+o].
__global__ void build_wt(const float* __restrict__ w2a, const float* __restrict__ b2a,
                         const float* __restrict__ ra,
                         const float* __restrict__ w2b, const float* __restrict__ b2b,
                         const float* __restrict__ rb,
                         _Float16* __restrict__ Wt1, _Float16* __restrict__ Wt2) {
    int idx = blockIdx.x * 256 + threadIdx.x;
    if (idx < 17408) {                       // 32 * 544 (CIN=16)
        int o = idx / 544, k = idx % 544;
        float v;
        if (k < 512) {
            int m = k & 31, i = k >> 5;
            v = w2a[m * 512 + i * 32 + o];
        } else if (k < 528) {
            v = b2a[(k - 512) * 32 + o];
        } else {
            v = ra[(k - 528) * 32 + o];
        }
        Wt1[o * 544 + k] = (_Float16)v;
    } else if (idx < 52224) {                // + 32 * 1088 (CIN=32)
        int j = idx - 17408;
        int o = j / 1088, k = j % 1088;
        float v;
        if (k < 1024) {
            int m = k & 31, i = k >> 5;
            v = w2b[m * 1024 + i * 32 + o];
        } else if (k < 1056) {
            v = b2b[(k - 1024) * 32 + o];
        } else {
            v = rb[(k - 1056) * 32 + o];
        }
        Wt2[o * 1088 + k] = (_Float16)v;
    }
}

// ---------------- edge kernel (zero-shuffle layout) ----------------
// One wave per node. Lane owns m = lane&31 and i in [ihalf, ihalf+JS),
// ihalf = (lane>>5)*JS. h[m] = silu(ew*w1[m]+b1[m]) computed by the lane
// itself (upper half duplicates, free). x row half loaded as float4s
// (same-address broadcast within half-wave, L1/L2-resident).
// F row (fp16): [inv*S at k=32*i+m (32*CIN) | inv*S0 (CIN) | x[d] (CIN)].

template <int CIN>
__global__ __launch_bounds__(256, 4) void edge_kernel(
    const float* __restrict__ xin, const int* __restrict__ ssrc,
    const float* __restrict__ sew, const int* __restrict__ off,
    const float* __restrict__ invc, const float* __restrict__ w1,
    const float* __restrict__ b1, _Float16* __restrict__ F) {
    constexpr int K = 34 * CIN;
    constexpr int JS = (32 * CIN) / 64;     // 8 (CIN=16) or 16 (CIN=32)
    constexpr int NQ = JS / 4;              // float4s per lane: 2 or 4
    const int lane = threadIdx.x & 63;
    const int d = (blockIdx.x * 256 + threadIdx.x) >> 6;   // 5000 blocks * 4 waves
    const int m = lane & 31;
    const int ihalf = (lane >> 5) * JS;
    const int i0 = lane & (CIN - 1);

    const float w1v = w1[m];
    const float b1v = b1[m];

    float Sacc[JS];
    #pragma unroll
    for (int j = 0; j < JS; ++j) Sacc[j] = 0.f;
    float S0 = 0.f;

    const int e0 = off[d], e1 = off[d + 1];
    const float iv = invc[d];

    #pragma unroll 2
    for (int e = e0; e < e1; ++e) {
        const int sn = ssrc[e];
        const float ew = sew[e];
        const float4* xr = (const float4*)(xin + (size_t)sn * CIN) + (ihalf >> 2);
        float4 xv[NQ];
        #pragma unroll
        for (int q = 0; q < NQ; ++q) xv[q] = xr[q];
        const float x0 = xin[(size_t)sn * CIN + i0];
        const float hv = silu_f(fmaf(ew, w1v, b1v));
        #pragma unroll
        for (int q = 0; q < NQ; ++q) {
            Sacc[4 * q + 0] = fmaf(hv, xv[q].x, Sacc[4 * q + 0]);
            Sacc[4 * q + 1] = fmaf(hv, xv[q].y, Sacc[4 * q + 1]);
            Sacc[4 * q + 2] = fmaf(hv, xv[q].z, Sacc[4 * q + 2]);
            Sacc[4 * q + 3] = fmaf(hv, xv[q].w, Sacc[4 * q + 3]);
        }
        S0 += x0;
    }

    _Float16* Fr = F + (size_t)d * K;
    #pragma unroll
    for (int j = 0; j < JS; ++j)
        Fr[(ihalf + j) * 32 + m] = (_Float16)(Sacc[j] * iv);
    if (lane < CIN)
        Fr[32 * CIN + lane] = (_Float16)(S0 * iv);
    else if (lane < 2 * CIN)
        Fr[32 * CIN + lane] = (_Float16)xin[(size_t)d * CIN + (lane - CIN)];
}

// ---------------- MFMA gemm: out(NN x 32) = F(NN x K) @ Wt^T -------
// 32-node tile/block (grid 625). F tile staged whole in LDS (fp16, LDK=K+8).
// 4 waves: h = w&1 -> node half (16), kq = w>>1 -> K half; LDS reduce.
// mfma_f32_16x16x32_f16; A row m=l&15, k=(l>>4)*4+j in halves {k, k+16};
// B col n=l&15 same k; D col=l&15, row=(l>>4)*4+r  [m89-verified].

template <int CIN, bool DECODE>
__global__ __launch_bounds__(256) void gemm_mfma(
    const _Float16* __restrict__ F, const _Float16* __restrict__ Wt,
    const float* __restrict__ bias, float* __restrict__ outp,
    const float* __restrict__ dw, const float* __restrict__ db) {
    constexpr int K = 34 * CIN;
    constexpr int LDK = K + 8;
    extern __shared__ char smem[];
    _Float16* Fl = (_Float16*)smem;
    float* red = (float*)(smem + 32 * LDK * 2);

    const int t = threadIdx.x;
    const int n0 = blockIdx.x * 32;

    constexpr int UPR = K / 8;            // 16B units per row
    for (int u = t; u < 32 * UPR; u += 256) {
        int r = u / UPR, c = u % UPR;
        float4 v = *(const float4*)(F + (size_t)(n0 + r) * K + c * 8);
        *(float4*)((char*)Fl + ((size_t)r * LDK + c * 8) * 2) = v;
    }
    __syncthreads();

    const int l = t & 63, w = t >> 6;
    const int h = w & 1, kq = w >> 1;
    const int o16 = l & 15, g = l >> 4;

    const _Float16* Arow = Fl + (size_t)(h * 16 + o16) * LDK + g * 4;
    const _Float16* B0 = Wt + (size_t)o16 * K + g * 4;
    const _Float16* B1 = Wt + (size_t)(o16 + 16) * K + g * 4;

    f32x4 acc0 = {0.f, 0.f, 0.f, 0.f};
    f32x4 acc1 = {0.f, 0.f, 0.f, 0.f};

    constexpr int steps = K / 32;
    constexpr int mid = (steps + 1) / 2;
    const int sb = kq ? mid : 0;
    const int se = kq ? steps : mid;
    for (int s = sb; s < se; ++s) {
        const int k0 = s * 32;
        f16x4 alo = *(const f16x4*)(Arow + k0);
        f16x4 ahi = *(const f16x4*)(Arow + k0 + 16);
        f16x4 b0l = *(const f16x4*)(B0 + k0);
        f16x4 b0h = *(const f16x4*)(B0 + k0 + 16);
        f16x4 b1l = *(const f16x4*)(B1 + k0);
        f16x4 b1h = *(const f16x4*)(B1 + k0 + 16);
        f16x8 a, bb0, bb1;
        #pragma unroll
        for (int j = 0; j < 4; ++j) {
            a[j] = alo[j];  a[j + 4] = ahi[j];
            bb0[j] = b0l[j]; bb0[j + 4] = b0h[j];
            bb1[j] = b1l[j]; bb1[j + 4] = b1h[j];
        }
        acc0 = __builtin_amdgcn_mfma_f32_16x16x32_f16(a, bb0, acc0, 0, 0, 0);
        acc1 = __builtin_amdgcn_mfma_f32_16x16x32_f16(a, bb1, acc1, 0, 0, 0);
    }

    if (kq == 1) {
        #pragma unroll
        for (int r = 0; r < 4; ++r) {
            red[h * 1024 + (g * 4 + r) * 32 + o16]      = acc0[r];
            red[h * 1024 + (g * 4 + r) * 32 + 16 + o16] = acc1[r];
        }
    }
    __syncthreads();
    if (kq == 0) {
        #pragma unroll
        for (int r = 0; r < 4; ++r) {
            acc0[r] += red[h * 1024 + (g * 4 + r) * 32 + o16];
            acc1[r] += red[h * 1024 + (g * 4 + r) * 32 + 16 + o16];
        }
        const float bb0 = bias[o16], bb1 = bias[o16 + 16];
        const int nrow = n0 + h * 16 + g * 4;
        if (!DECODE) {
            #pragma unroll
            for (int r = 0; r < 4; ++r) {
                outp[(size_t)(nrow + r) * 32 + o16]      = silu_f(acc0[r] + bb0);
                outp[(size_t)(nrow + r) * 32 + 16 + o16] = silu_f(acc1[r] + bb1);
            }
        } else {
            const float w0 = dw[o16], w1v = dw[o16 + 16];
            const float dbv = db[0];
            #pragma unroll
            for (int r = 0; r < 4; ++r) {
                float p = silu_f(acc0[r] + bb0) * w0 + silu_f(acc1[r] + bb1) * w1v;
                p += __shfl_xor(p, 1);
                p += __shfl_xor(p, 2);
                p += __shfl_xor(p, 4);
                p += __shfl_xor(p, 8);
                if (o16 == 0) outp[nrow + r] = p + dbv;
            }
        }
    }
}

// ---------------- launch ----------------

extern "C" void kernel_launch(void* const* d_in, const int* in_sizes, int n_in,
                              void* d_out, int out_size, void* d_ws, size_t ws_size,
                              hipStream_t stream) {
    const float* x      = (const float*)d_in[0];
    const int*   ei     = (const int*)d_in[1];
    const float* ew     = (const float*)d_in[2];
    const float* en1_w1 = (const float*)d_in[3];
    const float* en1_b1 = (const float*)d_in[4];
    const float* en1_w2 = (const float*)d_in[5];
    const float* en1_b2 = (const float*)d_in[6];
    const float* root1  = (const float*)d_in[7];
    const float* bias1  = (const float*)d_in[8];
    const float* en2_w1 = (const float*)d_in[9];
    const float* en2_b1 = (const float*)d_in[10];
    const float* en2_w2 = (const float*)d_in[11];
    const float* en2_b2 = (const float*)d_in[12];
    const float* root2  = (const float*)d_in[13];
    const float* bias2  = (const float*)d_in[14];
    const float* dec_w  = (const float*)d_in[15];
    const float* dec_b  = (const float*)d_in[16];
    float* out = (float*)d_out;
    (void)in_sizes; (void)n_in; (void)out_size; (void)ws_size;

    char* wp = (char*)d_ws;
    auto alloc = [&](size_t bytes) {
        char* p = wp;
        wp += (bytes + 255) & ~(size_t)255;
        return p;
    };
    int*      cz   = (int*)alloc((size_t)2 * NN * 4);     // cnt | cur contiguous
    int*      cnt  = cz;
    int*      cur  = cz + NN;
    int*      off  = (int*)alloc((size_t)(NN + 1) * 4);
    float*    invc = (float*)alloc((size_t)NN * 4);
    int*      ssrc = (int*)alloc((size_t)EE * 4);
    float*    sew  = (float*)alloc((size_t)EE * 4);
    float*    h1   = (float*)alloc((size_t)NN * 32 * 4);
    _Float16* Wt1  = (_Float16*)alloc((size_t)17408 * 2);
    _Float16* Wt2  = (_Float16*)alloc((size_t)34816 * 2);
    _Float16* F16  = (_Float16*)alloc((size_t)NN * 1088 * 2);

    hipMemsetAsync(cz, 0, (size_t)2 * NN * 4, stream);

    count_kernel<<<(EE + 255) / 256, 256, 0, stream>>>(ei, cnt);
    scan_kernel<<<1, 1024, 0, stream>>>(cnt, off, invc);
    scatter_kernel<<<(EE + 255) / 256, 256, 0, stream>>>(ei, ew, off, cur, ssrc, sew);
    build_wt<<<(52224 + 255) / 256, 256, 0, stream>>>(en1_w2, en1_b2, root1,
                                                      en2_w2, en2_b2, root2, Wt1, Wt2);

    auto g1 = gemm_mfma<16, false>;
    auto g2 = gemm_mfma<32, true>;
    (void)hipFuncSetAttribute((const void*)g1,
                              hipFuncAttributeMaxDynamicSharedMemorySize, 163840);
    (void)hipFuncSetAttribute((const void*)g2,
                              hipFuncAttributeMaxDynamicSharedMemorySize, 163840);

    const size_t lds1 = (size_t)32 * (544 + 8) * 2 + 8192;
    const size_t lds2 = (size_t)32 * (1088 + 8) * 2 + 8192;

    edge_kernel<16><<<5000, 256, 0, stream>>>(x, ssrc, sew, off, invc,
                                              en1_w1, en1_b1, F16);
    gemm_mfma<16, false><<<625, 256, lds1, stream>>>(F16, Wt1, bias1, h1,
                                                     nullptr, nullptr);
    edge_kernel<32><<<5000, 256, 0, stream>>>(h1, ssrc, sew, off, invc,
                                              en2_w1, en2_b1, F16);
    gemm_mfma<32, true><<<625, 256, lds2, stream>>>(F16, Wt2, bias2, out,
                                                    dec_w, dec_b);
}

// Round 5
// 165.835 us; speedup vs baseline: 6.0703x; 1.0505x over previous
//
#include <hip/hip_runtime.h>
#include <hip/hip_bf16.h>

#define NN 20000
#define EE 160000
#define HH 32
#define MIDD 32

typedef _Float16 f16x4 __attribute__((ext_vector_type(4)));
typedef _Float16 f16x8 __attribute__((ext_vector_type(8)));
typedef float f32x4 __attribute__((ext_vector_type(4)));

__device__ __forceinline__ float silu_f(float v) {
    return __fdividef(v, 1.0f + __expf(-v));
}

// ---------------- prep kernels ----------------

__global__ void count_kernel(const int* __restrict__ ei, int* __restrict__ cnt) {
    int e = blockIdx.x * 256 + threadIdx.x;
    if (e < EE) atomicAdd(&cnt[ei[EE + e]], 1);
}

__global__ void scan_kernel(const int* __restrict__ cnt, int* __restrict__ off,
                            float* __restrict__ invc) {
    __shared__ int tot[1024];
    const int t = threadIdx.x;
    const int CH = 20;
    int base = t * CH;
    int loc[CH];
    int s = 0;
    #pragma unroll
    for (int r = 0; r < CH; ++r) {
        int idx = base + r;
        int c = (idx < NN) ? cnt[idx] : 0;
        loc[r] = s;
        s += c;
    }
    tot[t] = s;
    __syncthreads();
    for (int d = 1; d < 1024; d <<= 1) {
        int u = (t >= d) ? tot[t - d] : 0;
        __syncthreads();
        tot[t] += u;
        __syncthreads();
    }
    int basesum = (t == 0) ? 0 : tot[t - 1];
    #pragma unroll
    for (int r = 0; r < CH; ++r) {
        int idx = base + r;
        if (idx < NN) {
            off[idx] = basesum + loc[r];
            int c = cnt[idx];
            invc[idx] = 1.0f / fmaxf((float)c, 1.0f);
        }
    }
    if (t == 0) off[NN] = EE;
}

__global__ void scatter_kernel(const int* __restrict__ ei, const float* __restrict__ ewt,
                               const int* __restrict__ off, int* __restrict__ cur,
                               int* __restrict__ ssrc, float* __restrict__ sew) {
    int e = blockIdx.x * 256 + threadIdx.x;
    if (e < EE) {
        int d = ei[EE + e];
        int p = atomicAdd(&cur[d], 1);
        int pos = off[d] + p;
        ssrc[pos] = ei[e];
        sew[pos] = ewt[e];
    }
}

// Wt[o][k] fp16 transposed weights. S-part k = 32*i + m  ->  w2[m*(CIN*32)+i*32+o];
// tail1 k = 32*CIN + t -> b2[t*32+o]; tail2 k = 33*CIN + t -> root[t*32+o].
__global__ void build_wt(const float* __restrict__ w2a, const float* __restrict__ b2a,
                         const float* __restrict__ ra,
                         const float* __restrict__ w2b, const float* __restrict__ b2b,
                         const float* __restrict__ rb,
                         _Float16* __restrict__ Wt1, _Float16* __restrict__ Wt2) {
    int idx = blockIdx.x * 256 + threadIdx.x;
    if (idx < 17408) {                       // 32 * 544 (CIN=16)
        int o = idx / 544, k = idx % 544;
        float v;
        if (k < 512) {
            int m = k & 31, i = k >> 5;
            v = w2a[m * 512 + i * 32 + o];
        } else if (k < 528) {
            v = b2a[(k - 512) * 32 + o];
        } else {
            v = ra[(k - 528) * 32 + o];
        }
        Wt1[o * 544 + k] = (_Float16)v;
    } else if (idx < 52224) {                // + 32 * 1088 (CIN=32)
        int j = idx - 17408;
        int o = j / 1088, k = j % 1088;
        float v;
        if (k < 1024) {
            int m = k & 31, i = k >> 5;
            v = w2b[m * 1024 + i * 32 + o];
        } else if (k < 1056) {
            v = b2b[(k - 1024) * 32 + o];
        } else {
            v = rb[(k - 1056) * 32 + o];
        }
        Wt2[o * 1088 + k] = (_Float16)v;
    }
}

// ---------------- edge kernel (zero-shuffle layout) ----------------

template <int CIN>
__global__ __launch_bounds__(256, 4) void edge_kernel(
    const float* __restrict__ xin, const int* __restrict__ ssrc,
    const float* __restrict__ sew, const int* __restrict__ off,
    const float* __restrict__ invc, const float* __restrict__ w1,
    const float* __restrict__ b1, _Float16* __restrict__ F) {
    constexpr int K = 34 * CIN;
    constexpr int JS = (32 * CIN) / 64;     // 8 (CIN=16) or 16 (CIN=32)
    constexpr int NQ = JS / 4;              // float4s per lane: 2 or 4
    const int lane = threadIdx.x & 63;
    const int d = (blockIdx.x * 256 + threadIdx.x) >> 6;   // 5000 blocks * 4 waves
    const int m = lane & 31;
    const int ihalf = (lane >> 5) * JS;
    const int i0 = lane & (CIN - 1);

    const float w1v = w1[m];
    const float b1v = b1[m];

    float Sacc[JS];
    #pragma unroll
    for (int j = 0; j < JS; ++j) Sacc[j] = 0.f;
    float S0 = 0.f;

    const int e0 = off[d], e1 = off[d + 1];
    const float iv = invc[d];

    #pragma unroll 2
    for (int e = e0; e < e1; ++e) {
        const int sn = ssrc[e];
        const float ew = sew[e];
        const float4* xr = (const float4*)(xin + (size_t)sn * CIN) + (ihalf >> 2);
        float4 xv[NQ];
        #pragma unroll
        for (int q = 0; q < NQ; ++q) xv[q] = xr[q];
        const float x0 = xin[(size_t)sn * CIN + i0];
        const float hv = silu_f(fmaf(ew, w1v, b1v));
        #pragma unroll
        for (int q = 0; q < NQ; ++q) {
            Sacc[4 * q + 0] = fmaf(hv, xv[q].x, Sacc[4 * q + 0]);
            Sacc[4 * q + 1] = fmaf(hv, xv[q].y, Sacc[4 * q + 1]);
            Sacc[4 * q + 2] = fmaf(hv, xv[q].z, Sacc[4 * q + 2]);
            Sacc[4 * q + 3] = fmaf(hv, xv[q].w, Sacc[4 * q + 3]);
        }
        S0 += x0;
    }

    _Float16* Fr = F + (size_t)d * K;
    #pragma unroll
    for (int j = 0; j < JS; ++j)
        Fr[(ihalf + j) * 32 + m] = (_Float16)(Sacc[j] * iv);
    if (lane < CIN)
        Fr[32 * CIN + lane] = (_Float16)(S0 * iv);
    else if (lane < 2 * CIN)
        Fr[32 * CIN + lane] = (_Float16)xin[(size_t)d * CIN + (lane - CIN)];
}

// ---------------- MFMA gemm, streaming (no LDS staging) --------------------
// Grid = NN/16 = 1250 blocks, 16-node tile per block. 4 waves split the
// K-steps (quarters, via (steps*q)/4 boundaries); A-frags loaded DIRECTLY
// from global F (16 rows x contiguous 64B per step — cacheline-perfect),
// B-frags from L2-resident Wt. Waves 1-3 dump partial acc to 6 KB LDS;
// wave 0 reduces + epilogue. Frag layouts identical to round-4 verified.

template <int CIN, bool DECODE>
__global__ __launch_bounds__(256, 4) void gemm_mfma(
    const _Float16* __restrict__ F, const _Float16* __restrict__ Wt,
    const float* __restrict__ bias, float* __restrict__ outp,
    const float* __restrict__ dw, const float* __restrict__ db) {
    constexpr int K = 34 * CIN;
    constexpr int steps = K / 32;            // 17 or 34
    __shared__ float red[3 * 512];

    const int t = threadIdx.x;
    const int n0 = blockIdx.x * 16;
    const int l = t & 63, w = t >> 6;
    const int o16 = l & 15, g = l >> 4;

    const _Float16* Arow = F + (size_t)(n0 + o16) * K + g * 4;
    const _Float16* B0 = Wt + (size_t)o16 * K + g * 4;
    const _Float16* B1 = Wt + (size_t)(o16 + 16) * K + g * 4;

    f32x4 acc0 = {0.f, 0.f, 0.f, 0.f};
    f32x4 acc1 = {0.f, 0.f, 0.f, 0.f};

    const int sb = (steps * w) >> 2;
    const int se = (steps * (w + 1)) >> 2;
    #pragma unroll 2
    for (int s = sb; s < se; ++s) {
        const int k0 = s * 32;
        f16x4 alo = *(const f16x4*)(Arow + k0);
        f16x4 ahi = *(const f16x4*)(Arow + k0 + 16);
        f16x4 b0l = *(const f16x4*)(B0 + k0);
        f16x4 b0h = *(const f16x4*)(B0 + k0 + 16);
        f16x4 b1l = *(const f16x4*)(B1 + k0);
        f16x4 b1h = *(const f16x4*)(B1 + k0 + 16);
        f16x8 a, bb0, bb1;
        #pragma unroll
        for (int j = 0; j < 4; ++j) {
            a[j] = alo[j];  a[j + 4] = ahi[j];
            bb0[j] = b0l[j]; bb0[j + 4] = b0h[j];
            bb1[j] = b1l[j]; bb1[j + 4] = b1h[j];
        }
        acc0 = __builtin_amdgcn_mfma_f32_16x16x32_f16(a, bb0, acc0, 0, 0, 0);
        acc1 = __builtin_amdgcn_mfma_f32_16x16x32_f16(a, bb1, acc1, 0, 0, 0);
    }

    if (w > 0) {
        float* rw = red + (w - 1) * 512;
        #pragma unroll
        for (int r = 0; r < 4; ++r) {
            rw[(g * 4 + r) * 32 + o16]      = acc0[r];
            rw[(g * 4 + r) * 32 + 16 + o16] = acc1[r];
        }
    }
    __syncthreads();
    if (w == 0) {
        #pragma unroll
        for (int r = 0; r < 4; ++r) {
            const int ro = (g * 4 + r) * 32 + o16;
            acc0[r] += red[ro] + red[512 + ro] + red[1024 + ro];
            acc1[r] += red[ro + 16] + red[512 + ro + 16] + red[1024 + ro + 16];
        }
        const float bb0 = bias[o16], bb1 = bias[o16 + 16];
        const int nrow = n0 + g * 4;
        if (!DECODE) {
            #pragma unroll
            for (int r = 0; r < 4; ++r) {
                outp[(size_t)(nrow + r) * 32 + o16]      = silu_f(acc0[r] + bb0);
                outp[(size_t)(nrow + r) * 32 + 16 + o16] = silu_f(acc1[r] + bb1);
            }
        } else {
            const float w0 = dw[o16], w1v = dw[o16 + 16];
            const float dbv = db[0];
            #pragma unroll
            for (int r = 0; r < 4; ++r) {
                float p = silu_f(acc0[r] + bb0) * w0 + silu_f(acc1[r] + bb1) * w1v;
                p += __shfl_xor(p, 1);
                p += __shfl_xor(p, 2);
                p += __shfl_xor(p, 4);
                p += __shfl_xor(p, 8);
                if (o16 == 0) outp[nrow + r] = p + dbv;
            }
        }
    }
}

// ---------------- launch ----------------

extern "C" void kernel_launch(void* const* d_in, const int* in_sizes, int n_in,
                              void* d_out, int out_size, void* d_ws, size_t ws_size,
                              hipStream_t stream) {
    const float* x      = (const float*)d_in[0];
    const int*   ei     = (const int*)d_in[1];
    const float* ew     = (const float*)d_in[2];
    const float* en1_w1 = (const float*)d_in[3];
    const float* en1_b1 = (const float*)d_in[4];
    const float* en1_w2 = (const float*)d_in[5];
    const float* en1_b2 = (const float*)d_in[6];
    const float* root1  = (const float*)d_in[7];
    const float* bias1  = (const float*)d_in[8];
    const float* en2_w1 = (const float*)d_in[9];
    const float* en2_b1 = (const float*)d_in[10];
    const float* en2_w2 = (const float*)d_in[11];
    const float* en2_b2 = (const float*)d_in[12];
    const float* root2  = (const float*)d_in[13];
    const float* bias2  = (const float*)d_in[14];
    const float* dec_w  = (const float*)d_in[15];
    const float* dec_b  = (const float*)d_in[16];
    float* out = (float*)d_out;
    (void)in_sizes; (void)n_in; (void)out_size; (void)ws_size;

    char* wp = (char*)d_ws;
    auto alloc = [&](size_t bytes) {
        char* p = wp;
        wp += (bytes + 255) & ~(size_t)255;
        return p;
    };
    int*      cz   = (int*)alloc((size_t)2 * NN * 4);     // cnt | cur contiguous
    int*      cnt  = cz;
    int*      cur  = cz + NN;
    int*      off  = (int*)alloc((size_t)(NN + 1) * 4);
    float*    invc = (float*)alloc((size_t)NN * 4);
    int*      ssrc = (int*)alloc((size_t)EE * 4);
    float*    sew  = (float*)alloc((size_t)EE * 4);
    float*    h1   = (float*)alloc((size_t)NN * 32 * 4);
    _Float16* Wt1  = (_Float16*)alloc((size_t)17408 * 2);
    _Float16* Wt2  = (_Float16*)alloc((size_t)34816 * 2);
    _Float16* F16  = (_Float16*)alloc((size_t)NN * 1088 * 2);

    hipMemsetAsync(cz, 0, (size_t)2 * NN * 4, stream);

    count_kernel<<<(EE + 255) / 256, 256, 0, stream>>>(ei, cnt);
    scan_kernel<<<1, 1024, 0, stream>>>(cnt, off, invc);
    scatter_kernel<<<(EE + 255) / 256, 256, 0, stream>>>(ei, ew, off, cur, ssrc, sew);
    build_wt<<<(52224 + 255) / 256, 256, 0, stream>>>(en1_w2, en1_b2, root1,
                                                      en2_w2, en2_b2, root2, Wt1, Wt2);

    edge_kernel<16><<<5000, 256, 0, stream>>>(x, ssrc, sew, off, invc,
                                              en1_w1, en1_b1, F16);
    gemm_mfma<16, false><<<NN / 16, 256, 0, stream>>>(F16, Wt1, bias1, h1,
                                                      nullptr, nullptr);
    edge_kernel<32><<<5000, 256, 0, stream>>>(h1, ssrc, sew, off, invc,
                                              en2_w1, en2_b1, F16);
    gemm_mfma<32, true><<<NN / 16, 256, 0, stream>>>(F16, Wt2, bias2, out,
                                                     dec_w, dec_b);
}

// Round 6
// 165.761 us; speedup vs baseline: 6.0730x; 1.0004x over previous
//
#include <hip/hip_runtime.h>
#include <hip/hip_bf16.h>

#define NN 20000
#define EE 160000
#define HH 32
#define MIDD 32

typedef _Float16 f16x4 __attribute__((ext_vector_type(4)));
typedef _Float16 f16x8 __attribute__((ext_vector_type(8)));
typedef float f32x4 __attribute__((ext_vector_type(4)));

__device__ __forceinline__ float silu_f(float v) {
    return __fdividef(v, 1.0f + __expf(-v));
}

// ---------------- prep kernels ----------------

__global__ void count_kernel(const int* __restrict__ ei, int* __restrict__ cnt) {
    int e = blockIdx.x * 256 + threadIdx.x;
    if (e < EE) atomicAdd(&cnt[ei[EE + e]], 1);
}

// writes off, a mutable copy cur (=off), and invc — scatter atomics hit cur,
// so no memset of cur is needed.
__global__ void scan_kernel(const int* __restrict__ cnt, int* __restrict__ off,
                            int* __restrict__ cur, float* __restrict__ invc) {
    __shared__ int tot[1024];
    const int t = threadIdx.x;
    const int CH = 20;
    int base = t * CH;
    int loc[CH];
    int s = 0;
    #pragma unroll
    for (int r = 0; r < CH; ++r) {
        int idx = base + r;
        int c = (idx < NN) ? cnt[idx] : 0;
        loc[r] = s;
        s += c;
    }
    tot[t] = s;
    __syncthreads();
    for (int d = 1; d < 1024; d <<= 1) {
        int u = (t >= d) ? tot[t - d] : 0;
        __syncthreads();
        tot[t] += u;
        __syncthreads();
    }
    int basesum = (t == 0) ? 0 : tot[t - 1];
    #pragma unroll
    for (int r = 0; r < CH; ++r) {
        int idx = base + r;
        if (idx < NN) {
            int o = basesum + loc[r];
            off[idx] = o;
            cur[idx] = o;
            invc[idx] = 1.0f / fmaxf((float)cnt[idx], 1.0f);
        }
    }
    if (t == 0) off[NN] = EE;
}

__global__ void scatter_kernel(const int* __restrict__ ei, const float* __restrict__ ewt,
                               int* __restrict__ cur,
                               int* __restrict__ ssrc, float* __restrict__ sew) {
    int e = blockIdx.x * 256 + threadIdx.x;
    if (e < EE) {
        int d = ei[EE + e];
        int pos = atomicAdd(&cur[d], 1);
        ssrc[pos] = ei[e];
        sew[pos] = ewt[e];
    }
}

// Wt[o][k] fp16 transposed weights. S-part k = 32*i + m  ->  w2[m*(CIN*32)+i*32+o];
// tail1 k = 32*CIN + t -> b2[t*32+o]; tail2 k = 33*CIN + t -> root[t*32+o].
__global__ void build_wt(const float* __restrict__ w2a, const float* __restrict__ b2a,
                         const float* __restrict__ ra,
                         const float* __restrict__ w2b, const float* __restrict__ b2b,
                         const float* __restrict__ rb,
                         _Float16* __restrict__ Wt1, _Float16* __restrict__ Wt2) {
    int idx = blockIdx.x * 256 + threadIdx.x;
    if (idx < 17408) {                       // 32 * 544 (CIN=16)
        int o = idx / 544, k = idx % 544;
        float v;
        if (k < 512) {
            int m = k & 31, i = k >> 5;
            v = w2a[m * 512 + i * 32 + o];
        } else if (k < 528) {
            v = b2a[(k - 512) * 32 + o];
        } else {
            v = ra[(k - 528) * 32 + o];
        }
        Wt1[o * 544 + k] = (_Float16)v;
    } else if (idx < 52224) {                // + 32 * 1088 (CIN=32)
        int j = idx - 17408;
        int o = j / 1088, k = j % 1088;
        float v;
        if (k < 1024) {
            int m = k & 31, i = k >> 5;
            v = w2b[m * 1024 + i * 32 + o];
        } else if (k < 1056) {
            v = b2b[(k - 1024) * 32 + o];
        } else {
            v = rb[(k - 1056) * 32 + o];
        }
        Wt2[o * 1088 + k] = (_Float16)v;
    }
}

// ---------------- fused layer kernel: edges -> LDS F -> MFMA gemm ----------
// Block (4 waves) owns 16 nodes. Phase A: wave w builds F rows for nodes
// n0+4w..n0+4w+3 with the zero-shuffle register pipeline (lane owns m=lane&31,
// i-range [(lane>>5)*JS, +JS)), writes each row into LDS Fl[node][k] fp16,
// LDK=K+4 (8B-aligned rows, dword-stride 546 == 2 mod 32 -> rotating banks).
// Phase B: verified MFMA body — 4 waves split K-steps, A-frags from LDS,
// B-frags from L2-resident Wt; waves 1-3 dump partials to red[]; wave 0
// reduces + bias/silu (+decode) epilogue.

template <int CIN, bool DECODE>
__global__ __launch_bounds__(256, 4) void fused_layer(
    const float* __restrict__ xin, const int* __restrict__ ssrc,
    const float* __restrict__ sew, const int* __restrict__ off,
    const float* __restrict__ invc, const float* __restrict__ w1,
    const float* __restrict__ b1, const _Float16* __restrict__ Wt,
    const float* __restrict__ bias, float* __restrict__ outp,
    const float* __restrict__ dw, const float* __restrict__ db) {
    constexpr int K = 34 * CIN;              // 544 or 1088
    constexpr int LDK = K + 4;
    constexpr int JS = (32 * CIN) / 64;      // 8 or 16
    constexpr int NQ = JS / 4;               // 2 or 4
    constexpr int steps = K / 32;            // 17 or 34

    __shared__ _Float16 Fl[16 * LDK];
    __shared__ float red[3 * 512];

    const int t = threadIdx.x;
    const int n0 = blockIdx.x * 16;
    const int lane = t & 63, w = t >> 6;

    // ---- Phase A ----
    {
        const int m = lane & 31;
        const int ihalf = (lane >> 5) * JS;
        const int i0 = lane & (CIN - 1);
        const float w1v = w1[m];
        const float b1v = b1[m];

        for (int c = 0; c < 4; ++c) {
            const int nsub = w * 4 + c;
            const int d = n0 + nsub;
            float Sacc[JS];
            #pragma unroll
            for (int j = 0; j < JS; ++j) Sacc[j] = 0.f;
            float S0 = 0.f;

            const int e0 = off[d], e1 = off[d + 1];
            const float iv = invc[d];

            #pragma unroll 2
            for (int e = e0; e < e1; ++e) {
                const int sn = ssrc[e];
                const float ew = sew[e];
                const float4* xr = (const float4*)(xin + (size_t)sn * CIN) + (ihalf >> 2);
                float4 xv[NQ];
                #pragma unroll
                for (int q = 0; q < NQ; ++q) xv[q] = xr[q];
                const float x0 = xin[(size_t)sn * CIN + i0];
                const float hv = silu_f(fmaf(ew, w1v, b1v));
                #pragma unroll
                for (int q = 0; q < NQ; ++q) {
                    Sacc[4 * q + 0] = fmaf(hv, xv[q].x, Sacc[4 * q + 0]);
                    Sacc[4 * q + 1] = fmaf(hv, xv[q].y, Sacc[4 * q + 1]);
                    Sacc[4 * q + 2] = fmaf(hv, xv[q].z, Sacc[4 * q + 2]);
                    Sacc[4 * q + 3] = fmaf(hv, xv[q].w, Sacc[4 * q + 3]);
                }
                S0 += x0;
            }

            _Float16* Fr = Fl + (size_t)nsub * LDK;
            #pragma unroll
            for (int j = 0; j < JS; ++j)
                Fr[(ihalf + j) * 32 + m] = (_Float16)(Sacc[j] * iv);
            if (lane < CIN)
                Fr[32 * CIN + lane] = (_Float16)(S0 * iv);
            else if (lane < 2 * CIN)
                Fr[32 * CIN + lane] = (_Float16)xin[(size_t)d * CIN + (lane - CIN)];
        }
    }
    __syncthreads();

    // ---- Phase B ----
    const int o16 = lane & 15, g = lane >> 4;

    const _Float16* Arow = Fl + (size_t)o16 * LDK + g * 4;
    const _Float16* B0 = Wt + (size_t)o16 * K + g * 4;
    const _Float16* B1 = Wt + (size_t)(o16 + 16) * K + g * 4;

    f32x4 acc0 = {0.f, 0.f, 0.f, 0.f};
    f32x4 acc1 = {0.f, 0.f, 0.f, 0.f};

    const int sb = (steps * w) >> 2;
    const int se = (steps * (w + 1)) >> 2;
    #pragma unroll 2
    for (int s = sb; s < se; ++s) {
        const int k0 = s * 32;
        f16x4 alo = *(const f16x4*)(Arow + k0);
        f16x4 ahi = *(const f16x4*)(Arow + k0 + 16);
        f16x4 b0l = *(const f16x4*)(B0 + k0);
        f16x4 b0h = *(const f16x4*)(B0 + k0 + 16);
        f16x4 b1l = *(const f16x4*)(B1 + k0);
        f16x4 b1h = *(const f16x4*)(B1 + k0 + 16);
        f16x8 a, bb0, bb1;
        #pragma unroll
        for (int j = 0; j < 4; ++j) {
            a[j] = alo[j];  a[j + 4] = ahi[j];
            bb0[j] = b0l[j]; bb0[j + 4] = b0h[j];
            bb1[j] = b1l[j]; bb1[j + 4] = b1h[j];
        }
        acc0 = __builtin_amdgcn_mfma_f32_16x16x32_f16(a, bb0, acc0, 0, 0, 0);
        acc1 = __builtin_amdgcn_mfma_f32_16x16x32_f16(a, bb1, acc1, 0, 0, 0);
    }

    if (w > 0) {
        float* rw = red + (w - 1) * 512;
        #pragma unroll
        for (int r = 0; r < 4; ++r) {
            rw[(g * 4 + r) * 32 + o16]      = acc0[r];
            rw[(g * 4 + r) * 32 + 16 + o16] = acc1[r];
        }
    }
    __syncthreads();
    if (w == 0) {
        #pragma unroll
        for (int r = 0; r < 4; ++r) {
            const int ro = (g * 4 + r) * 32 + o16;
            acc0[r] += red[ro] + red[512 + ro] + red[1024 + ro];
            acc1[r] += red[ro + 16] + red[512 + ro + 16] + red[1024 + ro + 16];
        }
        const float bb0 = bias[o16], bb1 = bias[o16 + 16];
        const int nrow = n0 + g * 4;
        if (!DECODE) {
            #pragma unroll
            for (int r = 0; r < 4; ++r) {
                outp[(size_t)(nrow + r) * 32 + o16]      = silu_f(acc0[r] + bb0);
                outp[(size_t)(nrow + r) * 32 + 16 + o16] = silu_f(acc1[r] + bb1);
            }
        } else {
            const float w0 = dw[o16], w1v = dw[o16 + 16];
            const float dbv = db[0];
            #pragma unroll
            for (int r = 0; r < 4; ++r) {
                float p = silu_f(acc0[r] + bb0) * w0 + silu_f(acc1[r] + bb1) * w1v;
                p += __shfl_xor(p, 1);
                p += __shfl_xor(p, 2);
                p += __shfl_xor(p, 4);
                p += __shfl_xor(p, 8);
                if (o16 == 0) outp[nrow + r] = p + dbv;
            }
        }
    }
}

// ---------------- launch ----------------

extern "C" void kernel_launch(void* const* d_in, const int* in_sizes, int n_in,
                              void* d_out, int out_size, void* d_ws, size_t ws_size,
                              hipStream_t stream) {
    const float* x      = (const float*)d_in[0];
    const int*   ei     = (const int*)d_in[1];
    const float* ew     = (const float*)d_in[2];
    const float* en1_w1 = (const float*)d_in[3];
    const float* en1_b1 = (const float*)d_in[4];
    const float* en1_w2 = (const float*)d_in[5];
    const float* en1_b2 = (const float*)d_in[6];
    const float* root1  = (const float*)d_in[7];
    const float* bias1  = (const float*)d_in[8];
    const float* en2_w1 = (const float*)d_in[9];
    const float* en2_b1 = (const float*)d_in[10];
    const float* en2_w2 = (const float*)d_in[11];
    const float* en2_b2 = (const float*)d_in[12];
    const float* root2  = (const float*)d_in[13];
    const float* bias2  = (const float*)d_in[14];
    const float* dec_w  = (const float*)d_in[15];
    const float* dec_b  = (const float*)d_in[16];
    float* out = (float*)d_out;
    (void)in_sizes; (void)n_in; (void)out_size; (void)ws_size;

    char* wp = (char*)d_ws;
    auto alloc = [&](size_t bytes) {
        char* p = wp;
        wp += (bytes + 255) & ~(size_t)255;
        return p;
    };
    int*      cnt  = (int*)alloc((size_t)NN * 4);
    int*      off  = (int*)alloc((size_t)(NN + 1) * 4);
    int*      cur  = (int*)alloc((size_t)NN * 4);
    float*    invc = (float*)alloc((size_t)NN * 4);
    int*      ssrc = (int*)alloc((size_t)EE * 4);
    float*    sew  = (float*)alloc((size_t)EE * 4);
    float*    h1   = (float*)alloc((size_t)NN * 32 * 4);
    _Float16* Wt1  = (_Float16*)alloc((size_t)17408 * 2);
    _Float16* Wt2  = (_Float16*)alloc((size_t)34816 * 2);

    hipMemsetAsync(cnt, 0, (size_t)NN * 4, stream);

    count_kernel<<<(EE + 255) / 256, 256, 0, stream>>>(ei, cnt);
    scan_kernel<<<1, 1024, 0, stream>>>(cnt, off, cur, invc);
    scatter_kernel<<<(EE + 255) / 256, 256, 0, stream>>>(ei, ew, cur, ssrc, sew);
    build_wt<<<(52224 + 255) / 256, 256, 0, stream>>>(en1_w2, en1_b2, root1,
                                                      en2_w2, en2_b2, root2, Wt1, Wt2);

    fused_layer<16, false><<<NN / 16, 256, 0, stream>>>(
        x, ssrc, sew, off, invc, en1_w1, en1_b1, Wt1, bias1, h1, nullptr, nullptr);
    fused_layer<32, true><<<NN / 16, 256, 0, stream>>>(
        h1, ssrc, sew, off, invc, en2_w1, en2_b1, Wt2, bias2, out, dec_w, dec_b);
}